// Round 1
// baseline (461.682 us; speedup 1.0000x reference)
//
#include <hip/hip_runtime.h>
#include <hip/hip_bf16.h>

#define B_ 4
#define L_ 8192
#define D_ 256
#define J_ 13

typedef __attribute__((ext_vector_type(4))) float f32x4;
typedef __attribute__((ext_vector_type(8))) short bf16x8;

// ---------------- W transpose: conv_w (256,512) f32 -> Wt (512,256) bf16 ----------
__global__ void wt_kernel(const float* __restrict__ W, __hip_bfloat16* __restrict__ Wt) {
    __shared__ float tile[64][65];
    int blk = blockIdx.x;            // 4 d-tiles x 8 e-tiles
    int dt = blk >> 3, et = blk & 7;
    int d0 = dt * 64, e0 = et * 64;
    int tid = threadIdx.x;
#pragma unroll
    for (int k = 0; k < 16; ++k) {
        int i = tid + k * 256;
        int r = i >> 6, c = i & 63;
        tile[r][c] = W[(d0 + r) * 512 + e0 + c];
    }
    __syncthreads();
#pragma unroll
    for (int k = 0; k < 16; ++k) {
        int i = tid + k * 256;
        int r = i >> 6, c = i & 63;   // write row e0+r, col d0+c
        Wt[(e0 + r) * 256 + d0 + c] = __float2bfloat16(tile[c][r]);
    }
}

// ---------------- K1: RMSNorm + transpose: x (B,L,D) f32 -> xt (B,D,L) f32 --------
__global__ void rms_kernel(const float* __restrict__ x, const float* __restrict__ scale,
                           float* __restrict__ xt) {
    __shared__ float tile[32][257];
    __shared__ float invl[32];
    int blk = blockIdx.x;            // b*256 + ltile
    int b  = blk >> 8;
    int l0 = (blk & 255) << 5;
    int tid = threadIdx.x;
    const float* src = x + ((size_t)(b * L_ + l0)) * D_;
#pragma unroll
    for (int k = 0; k < 32; ++k) tile[k][tid] = src[k * D_ + tid];
    __syncthreads();
    int wave = tid >> 6, lane = tid & 63;
#pragma unroll
    for (int rr = 0; rr < 8; ++rr) {
        int r = wave * 8 + rr;
        float s = 0.f;
#pragma unroll
        for (int q = 0; q < 4; ++q) { float v = tile[r][lane + 64 * q]; s += v * v; }
#pragma unroll
        for (int off = 32; off; off >>= 1) s += __shfl_xor(s, off);
        if (lane == 0) invl[r] = rsqrtf(s * (1.0f / 256.0f) + 1e-6f);
    }
    __syncthreads();
#pragma unroll
    for (int k = 0; k < 32; ++k) {
        int i = tid + k * 256;
        int d = i >> 5, lr = i & 31;
        float v = tile[lr][d] * invl[lr] * scale[d];
        xt[((size_t)(b * D_ + d)) * L_ + l0 + lr] = v;
    }
}

// ---------------- K2: 13-level dilated depthwise cascade + gelu ------------------
// one block per (b,c); whole sequence (8192 f32) in LDS
__global__ void __launch_bounds__(256) cascade_kernel(
    const float* __restrict__ xt, const float* __restrict__ h0,
    const float* __restrict__ h1, const float* __restrict__ w,
    __hip_bfloat16* __restrict__ ygt) {
    __shared__ float a[L_];
    int blk = blockIdx.x;            // b*256 + c
    int c = blk & 255;
    int tid = threadIdx.x;
    const float4* s4 = (const float4*)(xt + ((size_t)blk) * L_);
    float4* a4 = (float4*)a;
#pragma unroll
    for (int q = 0; q < 8; ++q) a4[tid + q * 256] = s4[tid + q * 256];
    float h00 = h0[c * 2], h01 = h0[c * 2 + 1];
    float h10 = h1[c * 2], h11 = h1[c * 2 + 1];
    float w0 = w[c], wlast = w[14 * D_ + c];
    __syncthreads();
    float cur[32], y[32];
#pragma unroll
    for (int m = 0; m < 32; ++m) {
        int t = tid + (m << 8);
        cur[m] = a[t];
        y[m] = w0 * cur[m];
    }
    for (int j = 0; j < J_; ++j) {
        int dil = 1 << j;
        float wj = w[(j + 1) * D_ + c];
        float prv[32];
#pragma unroll
        for (int m = 0; m < 32; ++m) {
            int t = tid + (m << 8);
            prv[m] = (t >= dil) ? a[t - dil] : 0.f;
        }
        __syncthreads();                    // all reads of level j-1 done
#pragma unroll
        for (int m = 0; m < 32; ++m) {
            int t = tid + (m << 8);
            float nv = h00 * prv[m] + h01 * cur[m];
            y[m] += wj * (h10 * prv[m] + h11 * cur[m]);
            cur[m] = nv;
            if (j < J_ - 1) a[t] = nv;
        }
        if (j < J_ - 1) __syncthreads();    // writes visible before next reads
    }
#pragma unroll
    for (int m = 0; m < 32; ++m) {
        int t = tid + (m << 8);
        float v = y[m] + wlast * cur[m];
        // gelu, tanh approximation (jax.nn.gelu default)
        float u = 0.7978845608028654f * (v + 0.044715f * v * v * v);
        float g = 0.5f * v * (1.f + tanhf(u));
        ygt[((size_t)blk) * L_ + t] = __float2bfloat16(g);
    }
}

// ---------------- K2.5: transpose ygt (B,D,L) bf16 -> yg (B,L,D) bf16 ------------
__global__ void trans_kernel(const ushort* __restrict__ ygt, ushort* __restrict__ yg) {
    __shared__ uint tile[64][33];
    int blk = blockIdx.x;            // b*512 + dt*128 + lt
    int b = blk >> 9;
    int rem = blk & 511;
    int dt = rem >> 7, lt = rem & 127;
    int d0 = dt * 64, l0 = lt * 64;
    int tid = threadIdx.x;
    const uint* src = (const uint*)ygt;
#pragma unroll
    for (int k = 0; k < 8; ++k) {
        int i = tid + k * 256;
        int r = i >> 5, cp = i & 31;
        tile[r][cp] = src[(((size_t)(b * D_ + d0 + r)) * L_ + l0) / 2 + cp];
    }
    __syncthreads();
    const ushort* ts = (const ushort*)tile;   // viewed as [64][66]
#pragma unroll
    for (int k = 0; k < 16; ++k) {
        int i = tid + k * 256;
        int r2 = i >> 6, c2 = i & 63;
        yg[((size_t)(b * L_ + l0 + r2)) * D_ + d0 + c2] = ts[c2 * 66 + r2];
    }
}

// ---------------- K3: bf16 MFMA GEMM + bias + GLU + residual ---------------------
// block tile: 128 l x 64 e-pairs (128 N-cols: 64 u | 64 v), K=256 in 4 chunks of 64
__global__ void __launch_bounds__(256) gemm_kernel(
    const ushort* __restrict__ yg, const ushort* __restrict__ Wt,
    const float* __restrict__ cb, const float* __restrict__ x,
    float* __restrict__ out) {
    __shared__ __align__(16) ushort As[128 * 72];
    __shared__ __align__(16) ushort Bs[128 * 72];
    int blk = blockIdx.x;            // b*256 + ltile*4 + etile
    int b = blk >> 8;
    int rem = blk & 255;
    int ltile = rem >> 2, et = rem & 3;
    int l0 = ltile * 128, e0 = et * 64;
    int tid = threadIdx.x;
    int wave = tid >> 6, lane = tid & 63;
    int wm = wave >> 1, wn = wave & 1;
    int m0 = wm * 64;
    f32x4 acc[4][4];
#pragma unroll
    for (int i = 0; i < 4; ++i)
#pragma unroll
        for (int j = 0; j < 4; ++j) acc[i][j] = (f32x4)0.f;

    for (int kc = 0; kc < 4; ++kc) {
        __syncthreads();
#pragma unroll
        for (int it = 0; it < 4; ++it) {   // A: 128 rows x 64 bf16
            int i = tid + it * 256;
            int r = i >> 3, seg = i & 7;
            const bf16x8* g = (const bf16x8*)(yg + ((size_t)(b * L_ + l0 + r)) * D_ + kc * 64 + seg * 8);
            *(bf16x8*)(As + r * 72 + seg * 8) = *g;
        }
#pragma unroll
        for (int it = 0; it < 4; ++it) {   // B: rows 0..63 = u cols, 64..127 = v cols
            int i = tid + it * 256;
            int n = i >> 3, seg = i & 7;
            int e = (n < 64) ? (e0 + n) : (256 + e0 + (n - 64));
            const bf16x8* g = (const bf16x8*)(Wt + e * 256 + kc * 64 + seg * 8);
            *(bf16x8*)(Bs + n * 72 + seg * 8) = *g;
        }
        __syncthreads();
#pragma unroll
        for (int kk = 0; kk < 2; ++kk) {
            bf16x8 af[4], bfr[4];
            int ko = kk * 32 + (lane >> 4) * 8;
#pragma unroll
            for (int mt = 0; mt < 4; ++mt)
                af[mt] = *(const bf16x8*)(As + (m0 + mt * 16 + (lane & 15)) * 72 + ko);
#pragma unroll
            for (int nt = 0; nt < 4; ++nt) {
                int n = wn * 32 + (nt & 1) * 16 + (nt >> 1) * 64 + (lane & 15);
                bfr[nt] = *(const bf16x8*)(Bs + n * 72 + ko);
            }
#pragma unroll
            for (int mt = 0; mt < 4; ++mt)
#pragma unroll
                for (int nt = 0; nt < 4; ++nt)
                    acc[mt][nt] = __builtin_amdgcn_mfma_f32_16x16x32_bf16(
                        af[mt], bfr[nt], acc[mt][nt], 0, 0, 0);
        }
    }
    // epilogue: u/v pair lives in the same lane (acc[mt][p] / acc[mt][p+2])
    int row_in = (lane >> 4) * 4;
    int col = lane & 15;
#pragma unroll
    for (int mt = 0; mt < 4; ++mt) {
#pragma unroll
        for (int p = 0; p < 2; ++p) {
            f32x4 uacc = acc[mt][p];
            f32x4 vacc = acc[mt][p + 2];
            int e = e0 + wn * 32 + p * 16 + col;
            float bu = cb[e], bv = cb[256 + e];
#pragma unroll
            for (int r = 0; r < 4; ++r) {
                int l = l0 + m0 + mt * 16 + row_in + r;
                float u = uacc[r] + bu;
                float v = vacc[r] + bv;
                float g = u / (1.f + __expf(-v));   // u * sigmoid(v)
                size_t idx = ((size_t)(b * L_ + l)) * D_ + e;
                out[idx] = g + x[idx];
            }
        }
    }
}

extern "C" void kernel_launch(void* const* d_in, const int* in_sizes, int n_in,
                              void* d_out, int out_size, void* d_ws, size_t ws_size,
                              hipStream_t stream) {
    const float* x  = (const float*)d_in[0];
    const float* rs = (const float*)d_in[1];
    const float* h0 = (const float*)d_in[2];
    const float* h1 = (const float*)d_in[3];
    const float* w  = (const float*)d_in[4];
    const float* cw = (const float*)d_in[5];
    const float* cb = (const float*)d_in[6];
    float* out = (float*)d_out;
    char* ws = (char*)d_ws;

    float*          xt  = (float*)ws;                            // 33,554,432 B
    __hip_bfloat16* ygt = (__hip_bfloat16*)(ws + 33554432);      // 16,777,216 B
    __hip_bfloat16* Wt  = (__hip_bfloat16*)(ws + 50331648);      //    262,144 B
    ushort*         yg  = (ushort*)ws;                           // alias xt (dead after cascade)

    wt_kernel<<<32, 256, 0, stream>>>(cw, Wt);
    rms_kernel<<<1024, 256, 0, stream>>>(x, rs, xt);
    cascade_kernel<<<1024, 256, 0, stream>>>(xt, h0, h1, w, ygt);
    trans_kernel<<<2048, 256, 0, stream>>>((const ushort*)ygt, yg);
    gemm_kernel<<<1024, 256, 0, stream>>>(yg, (const ushort*)Wt, cb, x, out);
}

// Round 2
// 271.992 us; speedup vs baseline: 1.6974x; 1.6974x over previous
//
#include <hip/hip_runtime.h>
#include <hip/hip_bf16.h>

#define B_ 4
#define L_ 8192
#define D_ 256
#define J_ 13

typedef __attribute__((ext_vector_type(4))) float f32x4;
typedef __attribute__((ext_vector_type(8))) short bf16x8;

// ---------------- W transpose: conv_w (256,512) f32 -> Wt (512,256) bf16 ----------
__global__ void wt_kernel(const float* __restrict__ W, __hip_bfloat16* __restrict__ Wt) {
    __shared__ float tile[64][65];
    int blk = blockIdx.x;            // 4 d-tiles x 8 e-tiles
    int dt = blk >> 3, et = blk & 7;
    int d0 = dt * 64, e0 = et * 64;
    int tid = threadIdx.x;
#pragma unroll
    for (int k = 0; k < 16; ++k) {
        int i = tid + k * 256;
        int r = i >> 6, c = i & 63;
        tile[r][c] = W[(d0 + r) * 512 + e0 + c];
    }
    __syncthreads();
#pragma unroll
    for (int k = 0; k < 16; ++k) {
        int i = tid + k * 256;
        int r = i >> 6, c = i & 63;   // write row e0+r, col d0+c
        Wt[(e0 + r) * 256 + d0 + c] = __float2bfloat16(tile[c][r]);
    }
}

// ---------------- K1: RMSNorm + transpose: x (B,L,D) f32 -> xt (B,D,L) f32 --------
__global__ void rms_kernel(const float* __restrict__ x, const float* __restrict__ scale,
                           float* __restrict__ xt) {
    __shared__ float tile[32][257];
    __shared__ float invl[32];
    int blk = blockIdx.x;            // b*256 + ltile
    int b  = blk >> 8;
    int l0 = (blk & 255) << 5;
    int tid = threadIdx.x;
    const float* src = x + ((size_t)(b * L_ + l0)) * D_;
#pragma unroll
    for (int k = 0; k < 32; ++k) tile[k][tid] = src[k * D_ + tid];
    __syncthreads();
    int wave = tid >> 6, lane = tid & 63;
#pragma unroll
    for (int rr = 0; rr < 8; ++rr) {
        int r = wave * 8 + rr;
        float s = 0.f;
#pragma unroll
        for (int q = 0; q < 4; ++q) { float v = tile[r][lane + 64 * q]; s += v * v; }
#pragma unroll
        for (int off = 32; off; off >>= 1) s += __shfl_xor(s, off);
        if (lane == 0) invl[r] = rsqrtf(s * (1.0f / 256.0f) + 1e-6f);
    }
    __syncthreads();
#pragma unroll
    for (int k = 0; k < 32; ++k) {
        int i = tid + k * 256;
        int d = i >> 5, lr = i & 31;
        float v = tile[lr][d] * invl[lr] * scale[d];
        xt[((size_t)(b * D_ + d)) * L_ + l0 + lr] = v;
    }
}

// ---------------- K2: 13-level dilated depthwise cascade + gelu ------------------
// one block per (b,c); double-buffered LDS ping-pong, float2 granularity.
// 512 threads x 8 float2 = 8192 elements. y-accumulator only state in VGPRs.
__global__ void __launch_bounds__(512) cascade_kernel(
    const float* __restrict__ xt, const float* __restrict__ h0,
    const float* __restrict__ h1, const float* __restrict__ w,
    __hip_bfloat16* __restrict__ ygt) {
    __shared__ float bufA[L_];
    __shared__ float bufB[L_];
    int blk = blockIdx.x;            // b*256 + c
    int c = blk & 255;
    int tid = threadIdx.x;
    const float4* s4 = (const float4*)(xt + ((size_t)blk) * L_);
    float4* a4 = (float4*)bufA;
#pragma unroll
    for (int q = 0; q < 4; ++q) a4[tid + q * 512] = s4[tid + q * 512];
    float h00 = h0[c * 2], h01 = h0[c * 2 + 1];
    float h10 = h1[c * 2], h11 = h1[c * 2 + 1];
    float w0 = w[c], wlast = w[14 * D_ + c];
    __syncthreads();

    float2 y[8];
    // ---- level 0 (dil = 1), fused with y init ----
    {
        float wj = w[1 * D_ + c];
        const float2* c2 = (const float2*)bufA;
        float2* n2 = (float2*)bufB;
#pragma unroll
        for (int m = 0; m < 8; ++m) {
            int p = tid + m * 512;
            float2 cv = c2[p];
            float px = (p > 0) ? bufA[2 * p - 1] : 0.f;
            float py = cv.x;
            y[m].x = w0 * cv.x + wj * (h10 * px + h11 * cv.x);
            y[m].y = w0 * cv.y + wj * (h10 * py + h11 * cv.y);
            n2[p] = make_float2(h00 * px + h01 * cv.x, h00 * py + h01 * cv.y);
        }
        __syncthreads();
    }
    float* cur = bufB;
    float* nxt = bufA;
    // ---- levels 1..12 (dil even -> aligned float2 taps) ----
    for (int j = 1; j < J_; ++j) {
        int dh = 1 << (j - 1);             // dil/2 in float2 units
        float wj = w[(j + 1) * D_ + c];
        const float2* c2 = (const float2*)cur;
        float2* n2 = (float2*)nxt;
#pragma unroll
        for (int m = 0; m < 8; ++m) {
            int p = tid + m * 512;
            float2 cv = c2[p];
            int q = p - dh;
            float2 pv = (q >= 0) ? c2[q] : make_float2(0.f, 0.f);
            y[m].x += wj * (h10 * pv.x + h11 * cv.x);
            y[m].y += wj * (h10 * pv.y + h11 * cv.y);
            n2[p] = make_float2(h00 * pv.x + h01 * cv.x, h00 * pv.y + h01 * cv.y);
        }
        __syncthreads();
        float* t = cur; cur = nxt; nxt = t;
    }
    // ---- epilogue: + wlast*a, gelu(tanh approx), bf16 store ----
    {
        const float2* c2 = (const float2*)cur;
        __hip_bfloat162* o2 = (__hip_bfloat162*)(ygt + ((size_t)blk) * L_);
#pragma unroll
        for (int m = 0; m < 8; ++m) {
            int p = tid + m * 512;
            float2 cv = c2[p];
            float vx = y[m].x + wlast * cv.x;
            float vy = y[m].y + wlast * cv.y;
            float ux = 0.7978845608028654f * (vx + 0.044715f * vx * vx * vx);
            float uy = 0.7978845608028654f * (vy + 0.044715f * vy * vy * vy);
            float gx = 0.5f * vx * (1.f + tanhf(ux));
            float gy = 0.5f * vy * (1.f + tanhf(uy));
            __hip_bfloat162 o;
            o.x = __float2bfloat16(gx);
            o.y = __float2bfloat16(gy);
            o2[p] = o;
        }
    }
}

// ---------------- K2.5: transpose ygt (B,D,L) bf16 -> yg (B,L,D) bf16 ------------
__global__ void trans_kernel(const ushort* __restrict__ ygt, ushort* __restrict__ yg) {
    __shared__ uint tile[64][33];
    int blk = blockIdx.x;            // b*512 + dt*128 + lt
    int b = blk >> 9;
    int rem = blk & 511;
    int dt = rem >> 7, lt = rem & 127;
    int d0 = dt * 64, l0 = lt * 64;
    int tid = threadIdx.x;
    const uint* src = (const uint*)ygt;
#pragma unroll
    for (int k = 0; k < 8; ++k) {
        int i = tid + k * 256;
        int r = i >> 5, cp = i & 31;
        tile[r][cp] = src[(((size_t)(b * D_ + d0 + r)) * L_ + l0) / 2 + cp];
    }
    __syncthreads();
    const ushort* ts = (const ushort*)tile;   // viewed as [64][66]
#pragma unroll
    for (int k = 0; k < 16; ++k) {
        int i = tid + k * 256;
        int r2 = i >> 6, c2 = i & 63;
        yg[((size_t)(b * L_ + l0 + r2)) * D_ + d0 + c2] = ts[c2 * 66 + r2];
    }
}

// ---------------- K3: bf16 MFMA GEMM + bias + GLU + residual ---------------------
// block tile: 128 l x 64 e-pairs (128 N-cols: 64 u | 64 v), K=256 in 4 chunks of 64
__global__ void __launch_bounds__(256) gemm_kernel(
    const ushort* __restrict__ yg, const ushort* __restrict__ Wt,
    const float* __restrict__ cb, const float* __restrict__ x,
    float* __restrict__ out) {
    __shared__ __align__(16) ushort As[128 * 72];
    __shared__ __align__(16) ushort Bs[128 * 72];
    int blk = blockIdx.x;            // b*256 + ltile*4 + etile
    int b = blk >> 8;
    int rem = blk & 255;
    int ltile = rem >> 2, et = rem & 3;
    int l0 = ltile * 128, e0 = et * 64;
    int tid = threadIdx.x;
    int wave = tid >> 6, lane = tid & 63;
    int wm = wave >> 1, wn = wave & 1;
    int m0 = wm * 64;
    f32x4 acc[4][4];
#pragma unroll
    for (int i = 0; i < 4; ++i)
#pragma unroll
        for (int j = 0; j < 4; ++j) acc[i][j] = (f32x4)0.f;

    for (int kc = 0; kc < 4; ++kc) {
        __syncthreads();
#pragma unroll
        for (int it = 0; it < 4; ++it) {   // A: 128 rows x 64 bf16
            int i = tid + it * 256;
            int r = i >> 3, seg = i & 7;
            const bf16x8* g = (const bf16x8*)(yg + ((size_t)(b * L_ + l0 + r)) * D_ + kc * 64 + seg * 8);
            *(bf16x8*)(As + r * 72 + seg * 8) = *g;
        }
#pragma unroll
        for (int it = 0; it < 4; ++it) {   // B: rows 0..63 = u cols, 64..127 = v cols
            int i = tid + it * 256;
            int n = i >> 3, seg = i & 7;
            int e = (n < 64) ? (e0 + n) : (256 + e0 + (n - 64));
            const bf16x8* g = (const bf16x8*)(Wt + e * 256 + kc * 64 + seg * 8);
            *(bf16x8*)(Bs + n * 72 + seg * 8) = *g;
        }
        __syncthreads();
#pragma unroll
        for (int kk = 0; kk < 2; ++kk) {
            bf16x8 af[4], bfr[4];
            int ko = kk * 32 + (lane >> 4) * 8;
#pragma unroll
            for (int mt = 0; mt < 4; ++mt)
                af[mt] = *(const bf16x8*)(As + (m0 + mt * 16 + (lane & 15)) * 72 + ko);
#pragma unroll
            for (int nt = 0; nt < 4; ++nt) {
                int n = wn * 32 + (nt & 1) * 16 + (nt >> 1) * 64 + (lane & 15);
                bfr[nt] = *(const bf16x8*)(Bs + n * 72 + ko);
            }
#pragma unroll
            for (int mt = 0; mt < 4; ++mt)
#pragma unroll
                for (int nt = 0; nt < 4; ++nt)
                    acc[mt][nt] = __builtin_amdgcn_mfma_f32_16x16x32_bf16(
                        af[mt], bfr[nt], acc[mt][nt], 0, 0, 0);
        }
    }
    // epilogue: u/v pair lives in the same lane (acc[mt][p] / acc[mt][p+2])
    int row_in = (lane >> 4) * 4;
    int col = lane & 15;
#pragma unroll
    for (int mt = 0; mt < 4; ++mt) {
#pragma unroll
        for (int p = 0; p < 2; ++p) {
            f32x4 uacc = acc[mt][p];
            f32x4 vacc = acc[mt][p + 2];
            int e = e0 + wn * 32 + p * 16 + col;
            float bu = cb[e], bv = cb[256 + e];
#pragma unroll
            for (int r = 0; r < 4; ++r) {
                int l = l0 + m0 + mt * 16 + row_in + r;
                float u = uacc[r] + bu;
                float v = vacc[r] + bv;
                float g = u / (1.f + __expf(-v));   // u * sigmoid(v)
                size_t idx = ((size_t)(b * L_ + l)) * D_ + e;
                out[idx] = g + x[idx];
            }
        }
    }
}

extern "C" void kernel_launch(void* const* d_in, const int* in_sizes, int n_in,
                              void* d_out, int out_size, void* d_ws, size_t ws_size,
                              hipStream_t stream) {
    const float* x  = (const float*)d_in[0];
    const float* rs = (const float*)d_in[1];
    const float* h0 = (const float*)d_in[2];
    const float* h1 = (const float*)d_in[3];
    const float* w  = (const float*)d_in[4];
    const float* cw = (const float*)d_in[5];
    const float* cb = (const float*)d_in[6];
    float* out = (float*)d_out;
    char* ws = (char*)d_ws;

    float*          xt  = (float*)ws;                            // 33,554,432 B
    __hip_bfloat16* ygt = (__hip_bfloat16*)(ws + 33554432);      // 16,777,216 B
    __hip_bfloat16* Wt  = (__hip_bfloat16*)(ws + 50331648);      //    262,144 B
    ushort*         yg  = (ushort*)ws;                           // alias xt (dead after cascade)

    wt_kernel<<<32, 256, 0, stream>>>(cw, Wt);
    rms_kernel<<<1024, 256, 0, stream>>>(x, rs, xt);
    cascade_kernel<<<1024, 512, 0, stream>>>(xt, h0, h1, w, ygt);
    trans_kernel<<<2048, 256, 0, stream>>>((const ushort*)ygt, yg);
    gemm_kernel<<<1024, 256, 0, stream>>>(yg, (const ushort*)Wt, cb, x, out);
}

// Round 3
// 184.882 us; speedup vs baseline: 2.4972x; 1.4712x over previous
//
#include <hip/hip_runtime.h>
#include <hip/hip_bf16.h>

#define B_ 4
#define L_ 8192
#define D_ 256
#define J_ 13

typedef __attribute__((ext_vector_type(4))) float f32x4;
typedef __attribute__((ext_vector_type(8))) short bf16x8;

// ---------------- W transpose: conv_w (256,512) f32 -> Wt (512,256) bf16 ----------
__global__ void wt_kernel(const float* __restrict__ W, __hip_bfloat16* __restrict__ Wt) {
    __shared__ float tile[64][65];
    int blk = blockIdx.x;            // 4 d-tiles x 8 e-tiles
    int dt = blk >> 3, et = blk & 7;
    int d0 = dt * 64, e0 = et * 64;
    int tid = threadIdx.x;
#pragma unroll
    for (int k = 0; k < 16; ++k) {
        int i = tid + k * 256;
        int r = i >> 6, c = i & 63;
        tile[r][c] = W[(d0 + r) * 512 + e0 + c];
    }
    __syncthreads();
#pragma unroll
    for (int k = 0; k < 16; ++k) {
        int i = tid + k * 256;
        int r = i >> 6, c = i & 63;   // write row e0+r, col d0+c
        Wt[(e0 + r) * 256 + d0 + c] = __float2bfloat16(tile[c][r]);
    }
}

// ---------------- K1: RMSNorm + transpose: x (B,L,D) f32 -> xt (B,D,L) f32 --------
__global__ void rms_kernel(const float* __restrict__ x, const float* __restrict__ scale,
                           float* __restrict__ xt) {
    __shared__ float tile[32][257];
    __shared__ float invl[32];
    int blk = blockIdx.x;            // b*256 + ltile
    int b  = blk >> 8;
    int l0 = (blk & 255) << 5;
    int tid = threadIdx.x;
    const float* src = x + ((size_t)(b * L_ + l0)) * D_;
#pragma unroll
    for (int k = 0; k < 32; ++k) tile[k][tid] = src[k * D_ + tid];
    __syncthreads();
    int wave = tid >> 6, lane = tid & 63;
#pragma unroll
    for (int rr = 0; rr < 8; ++rr) {
        int r = wave * 8 + rr;
        float s = 0.f;
#pragma unroll
        for (int q = 0; q < 4; ++q) { float v = tile[r][lane + 64 * q]; s += v * v; }
#pragma unroll
        for (int off = 32; off; off >>= 1) s += __shfl_xor(s, off);
        if (lane == 0) invl[r] = rsqrtf(s * (1.0f / 256.0f) + 1e-6f);
    }
    __syncthreads();
#pragma unroll
    for (int k = 0; k < 32; ++k) {
        int i = tid + k * 256;
        int d = i >> 5, lr = i & 31;
        float v = tile[lr][d] * invl[lr] * scale[d];
        xt[((size_t)(b * D_ + d)) * L_ + l0 + lr] = v;
    }
}

// ---------------- K2: 13-level dilated depthwise cascade + gelu ------------------
// one block per (b,c); double-buffered LDS ping-pong, float2 granularity.
// 512 threads x 8 float2 = 8192 elements. y-accumulator only state in VGPRs.
// #pragma unroll 1 on the level loop: full unroll caused cross-level software
// pipelining -> ~100 live VGPRs of hoisted LDS reads -> scratch spill (R2:
// FETCH 153MB vs 34MB ideal).
__global__ void __launch_bounds__(512, 4) cascade_kernel(
    const float* __restrict__ xt, const float* __restrict__ h0,
    const float* __restrict__ h1, const float* __restrict__ w,
    __hip_bfloat16* __restrict__ ygt) {
    __shared__ float bufA[L_];
    __shared__ float bufB[L_];
    int blk = blockIdx.x;            // b*256 + c
    int c = blk & 255;
    int tid = threadIdx.x;
    const float4* s4 = (const float4*)(xt + ((size_t)blk) * L_);
    float4* a4 = (float4*)bufA;
#pragma unroll
    for (int q = 0; q < 4; ++q) a4[tid + q * 512] = s4[tid + q * 512];
    float h00 = h0[c * 2], h01 = h0[c * 2 + 1];
    float h10 = h1[c * 2], h11 = h1[c * 2 + 1];
    float w0 = w[c], wlast = w[14 * D_ + c];
    __syncthreads();

    float2 y[8];
    // ---- level 0 (dil = 1), fused with y init ----
    {
        float wj = w[1 * D_ + c];
        const float2* c2 = (const float2*)bufA;
        float2* n2 = (float2*)bufB;
#pragma unroll
        for (int m = 0; m < 8; ++m) {
            int p = tid + m * 512;
            float2 cv = c2[p];
            float px = (p > 0) ? bufA[2 * p - 1] : 0.f;
            float py = cv.x;
            y[m].x = w0 * cv.x + wj * (h10 * px + h11 * cv.x);
            y[m].y = w0 * cv.y + wj * (h10 * py + h11 * cv.y);
            n2[p] = make_float2(h00 * px + h01 * cv.x, h00 * py + h01 * cv.y);
        }
        __syncthreads();
    }
    float* cur = bufB;
    float* nxt = bufA;
    // ---- levels 1..12 (dil even -> aligned float2 taps) ----
#pragma unroll 1
    for (int j = 1; j < J_; ++j) {
        int dh = 1 << (j - 1);             // dil/2 in float2 units
        float wj = w[(j + 1) * D_ + c];
        const float2* c2 = (const float2*)cur;
        float2* n2 = (float2*)nxt;
#pragma unroll
        for (int m = 0; m < 8; ++m) {
            int p = tid + m * 512;
            float2 cv = c2[p];
            int q = p - dh;
            float2 pv = (q >= 0) ? c2[q] : make_float2(0.f, 0.f);
            y[m].x += wj * (h10 * pv.x + h11 * cv.x);
            y[m].y += wj * (h10 * pv.y + h11 * cv.y);
            n2[p] = make_float2(h00 * pv.x + h01 * cv.x, h00 * pv.y + h01 * cv.y);
        }
        __syncthreads();
        float* t = cur; cur = nxt; nxt = t;
    }
    // ---- epilogue: + wlast*a, gelu(tanh approx), bf16 store ----
    {
        const float2* c2 = (const float2*)cur;
        __hip_bfloat162* o2 = (__hip_bfloat162*)(ygt + ((size_t)blk) * L_);
#pragma unroll
        for (int m = 0; m < 8; ++m) {
            int p = tid + m * 512;
            float2 cv = c2[p];
            float vx = y[m].x + wlast * cv.x;
            float vy = y[m].y + wlast * cv.y;
            float ux = 0.7978845608028654f * (vx + 0.044715f * vx * vx * vx);
            float uy = 0.7978845608028654f * (vy + 0.044715f * vy * vy * vy);
            float gx = 0.5f * vx * (1.f + tanhf(ux));
            float gy = 0.5f * vy * (1.f + tanhf(uy));
            __hip_bfloat162 o;
            o.x = __float2bfloat16(gx);
            o.y = __float2bfloat16(gy);
            o2[p] = o;
        }
    }
}

// ---------------- K2.5: transpose ygt (B,D,L) bf16 -> yg (B,L,D) bf16 ------------
__global__ void trans_kernel(const ushort* __restrict__ ygt, ushort* __restrict__ yg) {
    __shared__ uint tile[64][33];
    int blk = blockIdx.x;            // b*512 + dt*128 + lt
    int b = blk >> 9;
    int rem = blk & 511;
    int dt = rem >> 7, lt = rem & 127;
    int d0 = dt * 64, l0 = lt * 64;
    int tid = threadIdx.x;
    const uint* src = (const uint*)ygt;
#pragma unroll
    for (int k = 0; k < 8; ++k) {
        int i = tid + k * 256;
        int r = i >> 5, cp = i & 31;
        tile[r][cp] = src[(((size_t)(b * D_ + d0 + r)) * L_ + l0) / 2 + cp];
    }
    __syncthreads();
    const ushort* ts = (const ushort*)tile;   // viewed as [64][66]
#pragma unroll
    for (int k = 0; k < 16; ++k) {
        int i = tid + k * 256;
        int r2 = i >> 6, c2 = i & 63;
        yg[((size_t)(b * L_ + l0 + r2)) * D_ + d0 + c2] = ts[c2 * 66 + r2];
    }
}

// ---------------- K3: bf16 MFMA GEMM + bias + GLU + residual ---------------------
// block tile: 128 l x 64 e-pairs (128 N-cols: 64 u | 64 v), K=256 in 4 chunks of 64
__global__ void __launch_bounds__(256) gemm_kernel(
    const ushort* __restrict__ yg, const ushort* __restrict__ Wt,
    const float* __restrict__ cb, const float* __restrict__ x,
    float* __restrict__ out) {
    __shared__ __align__(16) ushort As[128 * 72];
    __shared__ __align__(16) ushort Bs[128 * 72];
    int blk = blockIdx.x;            // b*256 + ltile*4 + etile
    int b = blk >> 8;
    int rem = blk & 255;
    int ltile = rem >> 2, et = rem & 3;
    int l0 = ltile * 128, e0 = et * 64;
    int tid = threadIdx.x;
    int wave = tid >> 6, lane = tid & 63;
    int wm = wave >> 1, wn = wave & 1;
    int m0 = wm * 64;
    f32x4 acc[4][4];
#pragma unroll
    for (int i = 0; i < 4; ++i)
#pragma unroll
        for (int j = 0; j < 4; ++j) acc[i][j] = (f32x4)0.f;

    for (int kc = 0; kc < 4; ++kc) {
        __syncthreads();
#pragma unroll
        for (int it = 0; it < 4; ++it) {   // A: 128 rows x 64 bf16
            int i = tid + it * 256;
            int r = i >> 3, seg = i & 7;
            const bf16x8* g = (const bf16x8*)(yg + ((size_t)(b * L_ + l0 + r)) * D_ + kc * 64 + seg * 8);
            *(bf16x8*)(As + r * 72 + seg * 8) = *g;
        }
#pragma unroll
        for (int it = 0; it < 4; ++it) {   // B: rows 0..63 = u cols, 64..127 = v cols
            int i = tid + it * 256;
            int n = i >> 3, seg = i & 7;
            int e = (n < 64) ? (e0 + n) : (256 + e0 + (n - 64));
            const bf16x8* g = (const bf16x8*)(Wt + e * 256 + kc * 64 + seg * 8);
            *(bf16x8*)(Bs + n * 72 + seg * 8) = *g;
        }
        __syncthreads();
#pragma unroll
        for (int kk = 0; kk < 2; ++kk) {
            bf16x8 af[4], bfr[4];
            int ko = kk * 32 + (lane >> 4) * 8;
#pragma unroll
            for (int mt = 0; mt < 4; ++mt)
                af[mt] = *(const bf16x8*)(As + (m0 + mt * 16 + (lane & 15)) * 72 + ko);
#pragma unroll
            for (int nt = 0; nt < 4; ++nt) {
                int n = wn * 32 + (nt & 1) * 16 + (nt >> 1) * 64 + (lane & 15);
                bfr[nt] = *(const bf16x8*)(Bs + n * 72 + ko);
            }
#pragma unroll
            for (int mt = 0; mt < 4; ++mt)
#pragma unroll
                for (int nt = 0; nt < 4; ++nt)
                    acc[mt][nt] = __builtin_amdgcn_mfma_f32_16x16x32_bf16(
                        af[mt], bfr[nt], acc[mt][nt], 0, 0, 0);
        }
    }
    // epilogue: u/v pair lives in the same lane (acc[mt][p] / acc[mt][p+2])
    int row_in = (lane >> 4) * 4;
    int col = lane & 15;
#pragma unroll
    for (int mt = 0; mt < 4; ++mt) {
#pragma unroll
        for (int p = 0; p < 2; ++p) {
            f32x4 uacc = acc[mt][p];
            f32x4 vacc = acc[mt][p + 2];
            int e = e0 + wn * 32 + p * 16 + col;
            float bu = cb[e], bv = cb[256 + e];
#pragma unroll
            for (int r = 0; r < 4; ++r) {
                int l = l0 + m0 + mt * 16 + row_in + r;
                float u = uacc[r] + bu;
                float v = vacc[r] + bv;
                float g = u / (1.f + __expf(-v));   // u * sigmoid(v)
                size_t idx = ((size_t)(b * L_ + l)) * D_ + e;
                out[idx] = g + x[idx];
            }
        }
    }
}

extern "C" void kernel_launch(void* const* d_in, const int* in_sizes, int n_in,
                              void* d_out, int out_size, void* d_ws, size_t ws_size,
                              hipStream_t stream) {
    const float* x  = (const float*)d_in[0];
    const float* rs = (const float*)d_in[1];
    const float* h0 = (const float*)d_in[2];
    const float* h1 = (const float*)d_in[3];
    const float* w  = (const float*)d_in[4];
    const float* cw = (const float*)d_in[5];
    const float* cb = (const float*)d_in[6];
    float* out = (float*)d_out;
    char* ws = (char*)d_ws;

    float*          xt  = (float*)ws;                            // 33,554,432 B
    __hip_bfloat16* ygt = (__hip_bfloat16*)(ws + 33554432);      // 16,777,216 B
    __hip_bfloat16* Wt  = (__hip_bfloat16*)(ws + 50331648);      //    262,144 B
    ushort*         yg  = (ushort*)ws;                           // alias xt (dead after cascade)

    wt_kernel<<<32, 256, 0, stream>>>(cw, Wt);
    rms_kernel<<<1024, 256, 0, stream>>>(x, rs, xt);
    cascade_kernel<<<1024, 512, 0, stream>>>(xt, h0, h1, w, ygt);
    trans_kernel<<<2048, 256, 0, stream>>>((const ushort*)ygt, yg);
    gemm_kernel<<<1024, 256, 0, stream>>>(yg, (const ushort*)Wt, cb, x, out);
}

// Round 4
// 163.877 us; speedup vs baseline: 2.8172x; 1.1282x over previous
//
#include <hip/hip_runtime.h>
#include <hip/hip_bf16.h>

#define B_ 4
#define L_ 8192
#define D_ 256
#define J_ 13

typedef __attribute__((ext_vector_type(4))) float f32x4;
typedef __attribute__((ext_vector_type(8))) short bf16x8;

__device__ __forceinline__ void async_copy16(const void* g, void* l) {
    __builtin_amdgcn_global_load_lds(
        (const __attribute__((address_space(1))) void*)g,
        (__attribute__((address_space(3))) void*)l, 16, 0, 0);
}

// ---------------- W transpose: conv_w (256,512) f32 -> Wt (512,256) bf16 ----------
__global__ void wt_kernel(const float* __restrict__ W, __hip_bfloat16* __restrict__ Wt) {
    __shared__ float tile[64][65];
    int blk = blockIdx.x;            // 4 d-tiles x 8 e-tiles
    int dt = blk >> 3, et = blk & 7;
    int d0 = dt * 64, e0 = et * 64;
    int tid = threadIdx.x;
#pragma unroll
    for (int k = 0; k < 16; ++k) {
        int i = tid + k * 256;
        int r = i >> 6, c = i & 63;
        tile[r][c] = W[(d0 + r) * 512 + e0 + c];
    }
    __syncthreads();
#pragma unroll
    for (int k = 0; k < 16; ++k) {
        int i = tid + k * 256;
        int r = i >> 6, c = i & 63;   // write row e0+r, col d0+c
        Wt[(e0 + r) * 256 + d0 + c] = __float2bfloat16(tile[c][r]);
    }
}

// ---------------- K1: RMSNorm + transpose: x (B,L,D) f32 -> xt (B,D,L) f32 --------
__global__ void rms_kernel(const float* __restrict__ x, const float* __restrict__ scale,
                           float* __restrict__ xt) {
    __shared__ float tile[32][257];
    __shared__ float invl[32];
    int blk = blockIdx.x;            // b*256 + ltile
    int b  = blk >> 8;
    int l0 = (blk & 255) << 5;
    int tid = threadIdx.x;
    const float* src = x + ((size_t)(b * L_ + l0)) * D_;
#pragma unroll
    for (int k = 0; k < 32; ++k) tile[k][tid] = src[k * D_ + tid];
    __syncthreads();
    int wave = tid >> 6, lane = tid & 63;
#pragma unroll
    for (int rr = 0; rr < 8; ++rr) {
        int r = wave * 8 + rr;
        float s = 0.f;
#pragma unroll
        for (int q = 0; q < 4; ++q) { float v = tile[r][lane + 64 * q]; s += v * v; }
#pragma unroll
        for (int off = 32; off; off >>= 1) s += __shfl_xor(s, off);
        if (lane == 0) invl[r] = rsqrtf(s * (1.0f / 256.0f) + 1e-6f);
    }
    __syncthreads();
#pragma unroll
    for (int k = 0; k < 32; ++k) {
        int i = tid + k * 256;
        int d = i >> 5, lr = i & 31;
        float v = tile[lr][d] * invl[lr] * scale[d];
        xt[((size_t)(b * D_ + d)) * L_ + l0 + lr] = v;
    }
}

// ---------------- K2: 13-level dilated depthwise cascade + gelu ------------------
// one block per (b,c); double-buffered LDS ping-pong, float2 granularity.
// #pragma unroll 1 on the level loop: full unroll caused cross-level software
// pipelining -> ~100 live VGPRs of hoisted LDS reads -> scratch spill (R2).
__global__ void __launch_bounds__(512, 4) cascade_kernel(
    const float* __restrict__ xt, const float* __restrict__ h0,
    const float* __restrict__ h1, const float* __restrict__ w,
    __hip_bfloat16* __restrict__ ygt) {
    __shared__ float bufA[L_];
    __shared__ float bufB[L_];
    int blk = blockIdx.x;            // b*256 + c
    int c = blk & 255;
    int tid = threadIdx.x;
    const float4* s4 = (const float4*)(xt + ((size_t)blk) * L_);
    float4* a4 = (float4*)bufA;
#pragma unroll
    for (int q = 0; q < 4; ++q) a4[tid + q * 512] = s4[tid + q * 512];
    float h00 = h0[c * 2], h01 = h0[c * 2 + 1];
    float h10 = h1[c * 2], h11 = h1[c * 2 + 1];
    float w0 = w[c], wlast = w[14 * D_ + c];
    __syncthreads();

    float2 y[8];
    // ---- level 0 (dil = 1), fused with y init ----
    {
        float wj = w[1 * D_ + c];
        const float2* c2 = (const float2*)bufA;
        float2* n2 = (float2*)bufB;
#pragma unroll
        for (int m = 0; m < 8; ++m) {
            int p = tid + m * 512;
            float2 cv = c2[p];
            float px = (p > 0) ? bufA[2 * p - 1] : 0.f;
            float py = cv.x;
            y[m].x = w0 * cv.x + wj * (h10 * px + h11 * cv.x);
            y[m].y = w0 * cv.y + wj * (h10 * py + h11 * cv.y);
            n2[p] = make_float2(h00 * px + h01 * cv.x, h00 * py + h01 * cv.y);
        }
        __syncthreads();
    }
    float* cur = bufB;
    float* nxt = bufA;
    // ---- levels 1..12 (dil even -> aligned float2 taps) ----
#pragma unroll 1
    for (int j = 1; j < J_; ++j) {
        int dh = 1 << (j - 1);             // dil/2 in float2 units
        float wj = w[(j + 1) * D_ + c];
        const float2* c2 = (const float2*)cur;
        float2* n2 = (float2*)nxt;
#pragma unroll
        for (int m = 0; m < 8; ++m) {
            int p = tid + m * 512;
            float2 cv = c2[p];
            int q = p - dh;
            float2 pv = (q >= 0) ? c2[q] : make_float2(0.f, 0.f);
            y[m].x += wj * (h10 * pv.x + h11 * cv.x);
            y[m].y += wj * (h10 * pv.y + h11 * cv.y);
            n2[p] = make_float2(h00 * pv.x + h01 * cv.x, h00 * pv.y + h01 * cv.y);
        }
        __syncthreads();
        float* t = cur; cur = nxt; nxt = t;
    }
    // ---- epilogue: + wlast*a, gelu(tanh approx), bf16 store ----
    {
        const float2* c2 = (const float2*)cur;
        __hip_bfloat162* o2 = (__hip_bfloat162*)(ygt + ((size_t)blk) * L_);
#pragma unroll
        for (int m = 0; m < 8; ++m) {
            int p = tid + m * 512;
            float2 cv = c2[p];
            float vx = y[m].x + wlast * cv.x;
            float vy = y[m].y + wlast * cv.y;
            float ux = 0.7978845608028654f * (vx + 0.044715f * vx * vx * vx);
            float uy = 0.7978845608028654f * (vy + 0.044715f * vy * vy * vy);
            float gx = 0.5f * vx * (1.f + tanhf(ux));
            float gy = 0.5f * vy * (1.f + tanhf(uy));
            __hip_bfloat162 o;
            o.x = __float2bfloat16(gx);
            o.y = __float2bfloat16(gy);
            o2[p] = o;
        }
    }
}

// ---------------- K2.5: transpose ygt (B,D,L) bf16 -> yg (B,L,D) bf16 ------------
__global__ void trans_kernel(const ushort* __restrict__ ygt, ushort* __restrict__ yg) {
    __shared__ uint tile[64][33];
    int blk = blockIdx.x;            // b*512 + dt*128 + lt
    int b = blk >> 9;
    int rem = blk & 511;
    int dt = rem >> 7, lt = rem & 127;
    int d0 = dt * 64, l0 = lt * 64;
    int tid = threadIdx.x;
    const uint* src = (const uint*)ygt;
#pragma unroll
    for (int k = 0; k < 8; ++k) {
        int i = tid + k * 256;
        int r = i >> 5, cp = i & 31;
        tile[r][cp] = src[(((size_t)(b * D_ + d0 + r)) * L_ + l0) / 2 + cp];
    }
    __syncthreads();
    const ushort* ts = (const ushort*)tile;   // viewed as [64][66]
#pragma unroll
    for (int k = 0; k < 16; ++k) {
        int i = tid + k * 256;
        int r2 = i >> 6, c2 = i & 63;
        yg[((size_t)(b * L_ + l0 + r2)) * D_ + d0 + c2] = ts[c2 * 66 + r2];
    }
}

// ---------------- K3: bf16 MFMA GEMM + bias + GLU + residual ---------------------
// block tile: 128 l x 64 e-pairs (128 N-cols: 64 u | 64 v), K=256 in 4 chunks of 64
// Async global_load_lds staging into XOR-swizzled unpadded LDS (granule
// g' = g ^ (row&7)); epilogue repacks GLU output through LDS for float4 x/out.
__global__ void __launch_bounds__(256) gemm_kernel(
    const ushort* __restrict__ yg, const ushort* __restrict__ Wt,
    const float* __restrict__ cb, const float* __restrict__ x,
    float* __restrict__ out) {
    __shared__ __align__(16) char smem[32768];
    ushort* As = (ushort*)smem;            // [128 rows][8 granules of 8 bf16]
    ushort* Bs = As + 128 * 64;            // same shape
    int blk = blockIdx.x;            // b*256 + ltile*4 + etile
    int b = blk >> 8;
    int rem = blk & 255;
    int ltile = rem >> 2, et = rem & 3;
    int l0 = ltile * 128, e0 = et * 64;
    int tid = threadIdx.x;
    int wave = tid >> 6, lane = tid & 63;
    int wm = wave >> 1, wn = wave & 1;
    int m0 = wm * 64;

    // per-lane staging geometry (same for A and B): wave covers rows
    // [wave*32, wave*32+32) in 4 volleys of 8 rows; lane -> (row, granule')
    int srow_in = (lane >> 3);             // 0..7 within volley
    int sg = lane & 7;                     // swizzled granule g'
    int sgg = sg ^ srow_in;                // unswizzled granule g  (row&7 == srow_in)
    f32x4 acc[4][4];
#pragma unroll
    for (int i = 0; i < 4; ++i)
#pragma unroll
        for (int j = 0; j < 4; ++j) acc[i][j] = (f32x4)0.f;

    for (int kc = 0; kc < 4; ++kc) {
        __syncthreads();                   // previous compute done; LDS reusable
#pragma unroll
        for (int v = 0; v < 4; ++v) {
            int r = wave * 32 + v * 8 + srow_in;
            // A: row r -> yg row l0+r, cols kc*64 + g*8
            async_copy16(yg + ((size_t)(b * L_ + l0 + r)) * D_ + kc * 64 + sgg * 8,
                         As + r * 64 + sg * 8);
            // B: row r -> Wt row e (u: e0+r, v: 256+e0+r-64)
            int e = (r < 64) ? (e0 + r) : (256 + e0 + (r - 64));
            async_copy16(Wt + e * 256 + kc * 64 + sgg * 8,
                         Bs + r * 64 + sg * 8);
        }
        __syncthreads();                   // vmcnt(0) drained by compiler
#pragma unroll
        for (int kk = 0; kk < 2; ++kk) {
            bf16x8 af[4], bfr[4];
            int g = kk * 4 + (lane >> 4);
            int gp = (g ^ (lane & 7)) * 8;  // row&7 == lane&7 for all tiles
#pragma unroll
            for (int mt = 0; mt < 4; ++mt)
                af[mt] = *(const bf16x8*)(As + (m0 + mt * 16 + (lane & 15)) * 64 + gp);
#pragma unroll
            for (int nt = 0; nt < 4; ++nt) {
                int n = wn * 32 + (nt & 1) * 16 + (nt >> 1) * 64 + (lane & 15);
                bfr[nt] = *(const bf16x8*)(Bs + n * 64 + gp);
            }
#pragma unroll
            for (int mt = 0; mt < 4; ++mt)
#pragma unroll
                for (int nt = 0; nt < 4; ++nt)
                    acc[mt][nt] = __builtin_amdgcn_mfma_f32_16x16x32_bf16(
                        af[mt], bfr[nt], acc[mt][nt], 0, 0, 0);
        }
    }
    // ---- epilogue: GLU into LDS f32 [128 l][64 e] (e XOR 16 when l&4), then
    //      coalesced float4 read-back + x add + store ----
    __syncthreads();
    float* epi = (float*)smem;
    int row_in = (lane >> 4) * 4;
    int col = lane & 15;
#pragma unroll
    for (int mt = 0; mt < 4; ++mt) {
#pragma unroll
        for (int p = 0; p < 2; ++p) {
            f32x4 uacc = acc[mt][p];
            f32x4 vacc = acc[mt][p + 2];
            int ee = wn * 32 + p * 16 + col;
            float bu = cb[e0 + ee], bv = cb[256 + e0 + ee];
#pragma unroll
            for (int r = 0; r < 4; ++r) {
                int ll = m0 + mt * 16 + row_in + r;
                float u = uacc[r] + bu;
                float v = vacc[r] + bv;
                float g = u / (1.f + __expf(-v));
                epi[ll * 64 + (ee ^ ((ll & 4) ? 16 : 0))] = g;
            }
        }
    }
    __syncthreads();
#pragma unroll
    for (int k = 0; k < 8; ++k) {
        int i = tid + k * 256;             // 2048 float4 slots
        int ll = i >> 4, e4 = i & 15;
        int ex = (e4 * 4) ^ ((ll & 4) ? 16 : 0);
        float4 gv = *(const float4*)(epi + ll * 64 + ex);
        size_t gidx = ((size_t)(b * L_ + l0 + ll)) * D_ + e0 + e4 * 4;
        float4 xv = *(const float4*)(x + gidx);
        float4 ov;
        ov.x = gv.x + xv.x; ov.y = gv.y + xv.y;
        ov.z = gv.z + xv.z; ov.w = gv.w + xv.w;
        *(float4*)(out + gidx) = ov;
    }
}

extern "C" void kernel_launch(void* const* d_in, const int* in_sizes, int n_in,
                              void* d_out, int out_size, void* d_ws, size_t ws_size,
                              hipStream_t stream) {
    const float* x  = (const float*)d_in[0];
    const float* rs = (const float*)d_in[1];
    const float* h0 = (const float*)d_in[2];
    const float* h1 = (const float*)d_in[3];
    const float* w  = (const float*)d_in[4];
    const float* cw = (const float*)d_in[5];
    const float* cb = (const float*)d_in[6];
    float* out = (float*)d_out;
    char* ws = (char*)d_ws;

    float*          xt  = (float*)ws;                            // 33,554,432 B
    __hip_bfloat16* ygt = (__hip_bfloat16*)(ws + 33554432);      // 16,777,216 B
    __hip_bfloat16* Wt  = (__hip_bfloat16*)(ws + 50331648);      //    262,144 B
    ushort*         yg  = (ushort*)ws;                           // alias xt (dead after cascade)

    wt_kernel<<<32, 256, 0, stream>>>(cw, Wt);
    rms_kernel<<<1024, 256, 0, stream>>>(x, rs, xt);
    cascade_kernel<<<1024, 512, 0, stream>>>(xt, h0, h1, w, ygt);
    trans_kernel<<<2048, 256, 0, stream>>>((const ushort*)ygt, yg);
    gemm_kernel<<<1024, 256, 0, stream>>>(yg, (const ushort*)Wt, cb, x, out);
}